// Round 2
// baseline (1188.226 us; speedup 1.0000x reference)
//
#include <hip/hip_runtime.h>

typedef unsigned short u16;
typedef __attribute__((ext_vector_type(8))) __bf16 bf16x8;
typedef __attribute__((ext_vector_type(4))) float f32x4;
typedef __attribute__((ext_vector_type(4))) int i32x4;

#define MROWS 39200   // 200*196
#define MPAD  39296   // 307*128
#define KDIM  768

__device__ __forceinline__ u16 f2bf(float f) {
  unsigned u = __float_as_uint(f);
  return (u16)((u + 0x7fffu + ((u >> 16) & 1u)) >> 16);
}
__device__ __forceinline__ float bf2f(u16 b) {
  return __uint_as_float(((unsigned)b) << 16);
}
__device__ __forceinline__ f32x4 zero4() {
  f32x4 z; z[0] = 0.f; z[1] = 0.f; z[2] = 0.f; z[3] = 0.f; return z;
}
__device__ __forceinline__ void glds16(const void* g, void* l) {
  __builtin_amdgcn_global_load_lds((const __attribute__((address_space(1))) void*)(g),
                                   (__attribute__((address_space(3))) void*)(l), 16, 0, 0);
}

// ---------------- convert x (fp32 -> bf16), 8 elems/thread ----------------
__global__ __launch_bounds__(256) void k_convert_x(const float* __restrict__ x,
                                                   u16* __restrict__ xb) {
  int idx = blockIdx.x * 256 + threadIdx.x;  // 30105600/8 = 3763200 threads
  if (idx >= 3763200) return;
  f32x4 a = ((const f32x4*)x)[(size_t)idx * 2];
  f32x4 c = ((const f32x4*)x)[(size_t)idx * 2 + 1];
  u16 o[8];
  o[0] = f2bf(a[0]); o[1] = f2bf(a[1]); o[2] = f2bf(a[2]); o[3] = f2bf(a[3]);
  o[4] = f2bf(c[0]); o[5] = f2bf(c[1]); o[6] = f2bf(c[2]); o[7] = f2bf(c[3]);
  ((i32x4*)xb)[idx] = *(i32x4*)o;
}

// --------------- transpose+convert weights: w[K][N] -> wT[N][K] bf16 ------
__global__ __launch_bounds__(256) void k_transpose_w(const float* __restrict__ w,
                                                     u16* __restrict__ wT,
                                                     int K, int N, int total) {
  int idx = blockIdx.x * 256 + threadIdx.x;
  if (idx >= total) return;
  int n = idx / K, k = idx - n * K;
  wT[idx] = f2bf(w[(size_t)k * N + n]);  // wT[n*K+k]
}

// --------------- bf16 gemm_bt: C[M][N] = A[M][K] * B[N][K]^T --------------
// MODE 0: qkv epilogue (scatter to q/k/v bufs, +b_qkv). MODE 1: proj (+b_proj, fp32 out)
template <int MODE>
__global__ __launch_bounds__(256) void k_gemm(const u16* __restrict__ A,
                                              const u16* __restrict__ Bm,
                                              const float* __restrict__ bias,
                                              u16* __restrict__ o0,
                                              u16* __restrict__ o1,
                                              u16* __restrict__ o2,
                                              float* __restrict__ of) {
  __shared__ u16 a_sm[128 * 32];
  __shared__ u16 b_sm[128 * 32];
  const int tid = threadIdx.x, lane = tid & 63, wid = tid >> 6;
  const int tn = blockIdx.x, tm = blockIdx.y;
  const int lr = lane & 15, lg = lane >> 4;
  const int wm = wid >> 1, wn = wid & 1;

  const int o0b = wid * 2048 + lane * 16;
  const int o1b = o0b + 1024;
  const char* gA0 = (const char*)A + (size_t)(tm * 128 + (o0b >> 6)) * (KDIM * 2) + (o0b & 63);
  const char* gA1 = (const char*)A + (size_t)(tm * 128 + (o1b >> 6)) * (KDIM * 2) + (o1b & 63);
  const char* gB0 = (const char*)Bm + (size_t)(tn * 128 + (o0b >> 6)) * (KDIM * 2) + (o0b & 63);
  const char* gB1 = (const char*)Bm + (size_t)(tn * 128 + (o1b >> 6)) * (KDIM * 2) + (o1b & 63);
  char* lA0 = (char*)a_sm + wid * 2048;
  char* lA1 = lA0 + 1024;
  char* lB0 = (char*)b_sm + wid * 2048;
  char* lB1 = lB0 + 1024;

  f32x4 acc[4][4];
#pragma unroll
  for (int m = 0; m < 4; m++)
#pragma unroll
    for (int n = 0; n < 4; n++) acc[m][n] = zero4();

  for (int kt = 0; kt < KDIM / 32; kt++) {
    if (kt) __syncthreads();
    glds16(gA0 + kt * 64, lA0);
    glds16(gA1 + kt * 64, lA1);
    glds16(gB0 + kt * 64, lB0);
    glds16(gB1 + kt * 64, lB1);
    __syncthreads();
    bf16x8 af[4], bfr[4];
#pragma unroll
    for (int m = 0; m < 4; m++)
      af[m] = *(const bf16x8*)((const char*)a_sm + (wm * 64 + m * 16 + lr) * 64 + lg * 16);
#pragma unroll
    for (int n = 0; n < 4; n++)
      bfr[n] = *(const bf16x8*)((const char*)b_sm + (wn * 64 + n * 16 + lr) * 64 + lg * 16);
#pragma unroll
    for (int m = 0; m < 4; m++)
#pragma unroll
      for (int n = 0; n < 4; n++)
        acc[m][n] = __builtin_amdgcn_mfma_f32_16x16x32_bf16(af[m], bfr[n], acc[m][n], 0, 0, 0);
  }

#pragma unroll
  for (int n = 0; n < 4; n++) {
    int ng = tn * 128 + wn * 64 + n * 16 + lr;
    float bv = bias[ng];
#pragma unroll
    for (int m = 0; m < 4; m++) {
#pragma unroll
      for (int r = 0; r < 4; r++) {
        int mg = tm * 128 + wm * 64 + m * 16 + lg * 4 + r;
        if (mg < MROWS) {
          float val = acc[m][n][r] + bv;
          if (MODE == 0) {
            int which = ng / 768;
            int rem = ng - which * 768;
            int head = rem >> 6, d = rem & 63;
            int bi = mg / 196, i = mg - bi * 196;
            u16* dst = (which == 0) ? o0 : ((which == 1) ? o1 : o2);
            dst[((size_t)(bi * 12 + head) * 196 + i) * 64 + d] = f2bf(val);
          } else {
            of[(size_t)mg * 768 + ng] = val;
          }
        }
      }
    }
  }
}

// ---------------- fused attention, 1 WG per (batch, head) -----------------
// LDS layout (bytes):
#define SM_Q 0
#define SM_K 26624
#define SM_VT 53248          // [64][224] bf16
#define SM_P 81920           // [4 waves][16][224] bf16
#define SM_RH 110592         // [208][14] f32
#define SM_RW 122240
#define SM_TOTAL 133888

__global__ __launch_bounds__(256) void k_attn(const u16* __restrict__ qb,
                                              const u16* __restrict__ kb,
                                              const u16* __restrict__ vb,
                                              const float* __restrict__ rph,
                                              const float* __restrict__ rpw,
                                              u16* __restrict__ ao) {
  extern __shared__ char sm[];
  const int tid = threadIdx.x;
  const int bh = blockIdx.x;
  const size_t base = (size_t)bh * (196 * 64);

  // stage q,k (swizzled rows, stride 128B)
  for (int c = tid; c < 1568; c += 256) {
    int row = c >> 3, cb = (c & 7) << 4;
    int so = (row * 128 + cb) ^ ((row & 7) << 4);
    *(i32x4*)(sm + SM_Q + so) = *(const i32x4*)((const char*)(qb + base) + c * 16);
    *(i32x4*)(sm + SM_K + so) = *(const i32x4*)((const char*)(kb + base) + c * 16);
  }
  i32x4 zi; zi[0] = 0; zi[1] = 0; zi[2] = 0; zi[3] = 0;
  for (int c = tid; c < 96; c += 256) {  // zero pad rows 196..207
    int row = 196 + (c >> 3), cb = (c & 7) << 4;
    int so = (row * 128 + cb) ^ ((row & 7) << 4);
    *(i32x4*)(sm + SM_Q + so) = zi;
    *(i32x4*)(sm + SM_K + so) = zi;
  }
  // stage v transposed: vT[d][j], stride 448B, swizzled
  for (int c = tid; c < 1568; c += 256) {
    int j = c >> 3, d0 = (c & 7) << 3;
    i32x4 vv = *(const i32x4*)((const char*)(vb + base) + c * 16);
    const u16* u = (const u16*)&vv;
#pragma unroll
    for (int e = 0; e < 8; e++) {
      int d = d0 + e;
      int so = (d * 448 + j * 2) ^ ((d & 7) << 4);
      *(u16*)(sm + SM_VT + so) = u[e];
    }
  }
  for (int idx = tid; idx < 64 * 28; idx += 256) {  // zero vT cols 196..223
    int d = idx / 28, j = 196 + (idx - d * 28);
    int so = (d * 448 + j * 2) ^ ((d & 7) << 4);
    *(u16*)(sm + SM_VT + so) = 0;
  }
  for (int idx = tid; idx < 1024; idx += 256) {  // zero P cols 208..223
    int wv2 = idx >> 8, rem = idx & 255;
    int pr = rem >> 4, cc = 208 + (rem & 15);
    int so = wv2 * 7168 + ((pr * 448 + cc * 2) ^ ((pr & 7) << 4));
    *(u16*)(sm + SM_P + so) = 0;
  }
  __syncthreads();

  // rel tables: relh[i][kh] = dot(q[i,:], rel_pos_h[h(i)-kh+13,:]) ; same for w
  for (int e = tid; e < 208 * 14; e += 256) {
    int i = e / 14, kh = e - i * 14;
    float acc = 0.f;
    if (i < 196) {
      int h = i / 14;
      const float* R = rph + (h - kh + 13) * 64;
#pragma unroll
      for (int c8 = 0; c8 < 8; c8++) {
        int so = (i * 128 + c8 * 16) ^ ((i & 7) << 4);
        i32x4 v = *(const i32x4*)(sm + SM_Q + so);
        const u16* u = (const u16*)&v;
#pragma unroll
        for (int e2 = 0; e2 < 8; e2++) acc += bf2f(u[e2]) * R[c8 * 8 + e2];
      }
    }
    *(float*)(sm + SM_RH + e * 4) = acc;
  }
  for (int e = tid; e < 208 * 14; e += 256) {
    int i = e / 14, kw = e - i * 14;
    float acc = 0.f;
    if (i < 196) {
      int wq = i - (i / 14) * 14;
      const float* R = rpw + (wq - kw + 13) * 64;
#pragma unroll
      for (int c8 = 0; c8 < 8; c8++) {
        int so = (i * 128 + c8 * 16) ^ ((i & 7) << 4);
        i32x4 v = *(const i32x4*)(sm + SM_Q + so);
        const u16* u = (const u16*)&v;
#pragma unroll
        for (int e2 = 0; e2 < 8; e2++) acc += bf2f(u[e2]) * R[c8 * 8 + e2];
      }
    }
    *(float*)(sm + SM_RW + e * 4) = acc;
  }
  __syncthreads();

  const int lane = tid & 63, wv = tid >> 6;
  const int lr = lane & 15, lg = lane >> 4;
  const int bi = bh / 12, head = bh - bi * 12;

  for (int rt = wv; rt < 13; rt += 4) {
    int arow = rt * 16 + lr;
    bf16x8 aq0 = *(const bf16x8*)(sm + SM_Q + ((arow * 128 + lg * 16) ^ ((arow & 7) << 4)));
    bf16x8 aq1 = *(const bf16x8*)(sm + SM_Q + ((arow * 128 + 64 + lg * 16) ^ ((arow & 7) << 4)));
    f32x4 s[13];
#pragma unroll
    for (int j = 0; j < 13; j++) s[j] = zero4();
#pragma unroll
    for (int j = 0; j < 13; j++) {
      int brow = j * 16 + lr;
      bf16x8 bk0 = *(const bf16x8*)(sm + SM_K + ((brow * 128 + lg * 16) ^ ((brow & 7) << 4)));
      bf16x8 bk1 = *(const bf16x8*)(sm + SM_K + ((brow * 128 + 64 + lg * 16) ^ ((brow & 7) << 4)));
      s[j] = __builtin_amdgcn_mfma_f32_16x16x32_bf16(aq0, bk0, s[j], 0, 0, 0);
      s[j] = __builtin_amdgcn_mfma_f32_16x16x32_bf16(aq1, bk1, s[j], 0, 0, 0);
    }
    // bias + scale + softmax (rows owned by 16-lane groups; reduce via shfl_xor)
    float rs[4];
#pragma unroll
    for (int r = 0; r < 4; r++) {
      int qi = rt * 16 + lg * 4 + r;
      float mx = -3.0e38f;
#pragma unroll
      for (int j = 0; j < 13; j++) {
        int col = j * 16 + lr;
        float t;
        if (col < 196) {
          int kh = (col * 2341) >> 15;
          int kw = col - kh * 14;
          t = s[j][r] * 0.125f + *(const float*)(sm + SM_RH + (qi * 14 + kh) * 4)
                               + *(const float*)(sm + SM_RW + (qi * 14 + kw) * 4);
        } else {
          t = -3.0e38f;
        }
        s[j][r] = t;
        mx = fmaxf(mx, t);
      }
      mx = fmaxf(mx, __shfl_xor(mx, 1));
      mx = fmaxf(mx, __shfl_xor(mx, 2));
      mx = fmaxf(mx, __shfl_xor(mx, 4));
      mx = fmaxf(mx, __shfl_xor(mx, 8));
      float sum = 0.f;
#pragma unroll
      for (int j = 0; j < 13; j++) {
        float p = __expf(s[j][r] - mx);
        s[j][r] = p;
        sum += p;
      }
      sum += __shfl_xor(sum, 1);
      sum += __shfl_xor(sum, 2);
      sum += __shfl_xor(sum, 4);
      sum += __shfl_xor(sum, 8);
      rs[r] = 1.f / sum;
    }
    // P -> LDS (per-wave region) as bf16
#pragma unroll
    for (int r = 0; r < 4; r++) {
      int pr = lg * 4 + r;
#pragma unroll
      for (int j = 0; j < 13; j++) {
        int col = j * 16 + lr;
        int so = wv * 7168 + ((pr * 448 + col * 2) ^ ((pr & 7) << 4));
        *(u16*)(sm + SM_P + so) = f2bf(s[j][r]);
      }
    }
    // PV
    f32x4 ov[4];
#pragma unroll
    for (int d4 = 0; d4 < 4; d4++) ov[d4] = zero4();
#pragma unroll
    for (int kk = 0; kk < 7; kk++) {
      int soa = wv * 7168 + ((lr * 448 + kk * 64 + lg * 16) ^ ((lr & 7) << 4));
      bf16x8 pa = *(const bf16x8*)(sm + SM_P + soa);
#pragma unroll
      for (int d4 = 0; d4 < 4; d4++) {
        int vr = d4 * 16 + lr;
        int sob = (vr * 448 + kk * 64 + lg * 16) ^ ((vr & 7) << 4);
        bf16x8 vf = *(const bf16x8*)(sm + SM_VT + sob);
        ov[d4] = __builtin_amdgcn_mfma_f32_16x16x32_bf16(pa, vf, ov[d4], 0, 0, 0);
      }
    }
    // store (divide by row sum)
#pragma unroll
    for (int r = 0; r < 4; r++) {
      int i = rt * 16 + lg * 4 + r;
      if (i < 196) {
        size_t ro = ((size_t)(bi * 196 + i)) * 768 + head * 64;
#pragma unroll
        for (int d4 = 0; d4 < 4; d4++) {
          ao[ro + d4 * 16 + lr] = f2bf(ov[d4][r] * rs[r]);
        }
      }
    }
  }
}

// --------------------------------------------------------------------------
extern "C" void kernel_launch(void* const* d_in, const int* in_sizes, int n_in,
                              void* d_out, int out_size, void* d_ws, size_t ws_size,
                              hipStream_t stream) {
  const float* x = (const float*)d_in[0];
  const float* w_qkv = (const float*)d_in[1];
  const float* b_qkv = (const float*)d_in[2];
  const float* w_proj = (const float*)d_in[3];
  const float* b_proj = (const float*)d_in[4];
  const float* rph = (const float*)d_in[5];
  const float* rpw = (const float*)d_in[6];
  float* out = (float*)d_out;

  // workspace layout (aob aliases xb: xb dead after k_gemm<0>)
  char* ws = (char*)d_ws;
  u16* xb = (u16*)(ws + 0);                  // 39296*768*2   = 60358656
  u16* aob = (u16*)(ws + 0);                 // alias (attention output)
  u16* wqkvT = (u16*)(ws + 60358656);        // 2304*768*2    =  3538944
  u16* wprojT = (u16*)(ws + 63897600);       // 768*768*2     =  1179648
  u16* qbuf = (u16*)(ws + 65077248);         // 2400*196*64*2 = 60211200
  u16* kbuf = (u16*)(ws + 125288448);
  u16* vbuf = (u16*)(ws + 185499648);
  // end: 245710848 bytes
  if (ws_size < 245710848ULL) return;  // fail cleanly (wrong output), never OOB

  k_convert_x<<<14700, 256, 0, stream>>>(x, xb);
  k_transpose_w<<<6912, 256, 0, stream>>>(w_qkv, wqkvT, 768, 2304, 768 * 2304);
  k_transpose_w<<<2304, 256, 0, stream>>>(w_proj, wprojT, 768, 768, 768 * 768);

  k_gemm<0><<<dim3(18, 307), 256, 0, stream>>>(xb, wqkvT, b_qkv, qbuf, kbuf, vbuf, nullptr);

  hipFuncSetAttribute((const void*)k_attn, hipFuncAttributeMaxDynamicSharedMemorySize, SM_TOTAL);
  k_attn<<<2400, 256, SM_TOTAL, stream>>>(qbuf, kbuf, vbuf, rph, rpw, aob);

  k_gemm<1><<<dim3(6, 307), 256, 0, stream>>>(aob, wprojT, b_proj, nullptr, nullptr, nullptr, out);
}

// Round 3
// 988.650 us; speedup vs baseline: 1.2019x; 1.2019x over previous
//
#include <hip/hip_runtime.h>

typedef unsigned short u16;
typedef unsigned int u32;
typedef __attribute__((ext_vector_type(8))) __bf16 bf16x8;
typedef __attribute__((ext_vector_type(4))) float f32x4;
typedef __attribute__((ext_vector_type(4))) int i32x4;
typedef __attribute__((ext_vector_type(2))) int i32x2;

#define MROWS 39200   // 200*196
#define KDIM  768

__device__ __forceinline__ u16 f2bf(float f) {
  unsigned u = __float_as_uint(f);
  return (u16)((u + 0x7fffu + ((u >> 16) & 1u)) >> 16);
}
__device__ __forceinline__ float bf2f(u16 b) {
  return __uint_as_float(((unsigned)b) << 16);
}
__device__ __forceinline__ f32x4 zero4() {
  f32x4 z; z[0] = 0.f; z[1] = 0.f; z[2] = 0.f; z[3] = 0.f; return z;
}
__device__ __forceinline__ void glds16(const void* g, void* l) {
  __builtin_amdgcn_global_load_lds((const __attribute__((address_space(1))) void*)(g),
                                   (__attribute__((address_space(3))) void*)(l), 16, 0, 0);
}
__device__ __forceinline__ u32 cvt_pk_bf16(float lo, float hi) {
  u32 r;
  asm volatile("v_cvt_pk_bf16_f32 %0, %1, %2" : "=v"(r) : "v"(lo), "v"(hi));
  return r;
}

// ---------------- convert x (fp32 -> bf16), 8 elems/thread ----------------
__global__ __launch_bounds__(256) void k_convert_x(const float* __restrict__ x,
                                                   u16* __restrict__ xb) {
  int idx = blockIdx.x * 256 + threadIdx.x;
  if (idx >= 3763200) return;
  f32x4 a = ((const f32x4*)x)[(size_t)idx * 2];
  f32x4 c = ((const f32x4*)x)[(size_t)idx * 2 + 1];
  u16 o[8];
  o[0] = f2bf(a[0]); o[1] = f2bf(a[1]); o[2] = f2bf(a[2]); o[3] = f2bf(a[3]);
  o[4] = f2bf(c[0]); o[5] = f2bf(c[1]); o[6] = f2bf(c[2]); o[7] = f2bf(c[3]);
  ((i32x4*)xb)[idx] = *(i32x4*)o;
}

// --------------- transpose+convert weights: w[K][N] -> wT[N][K] bf16 ------
__global__ __launch_bounds__(256) void k_transpose_w(const float* __restrict__ w,
                                                     u16* __restrict__ wT,
                                                     int K, int N, int total) {
  int idx = blockIdx.x * 256 + threadIdx.x;
  if (idx >= total) return;
  int n = idx / K, k = idx - n * K;
  wT[idx] = f2bf(w[(size_t)k * N + n]);
}

// --------------- rel-pos B-matrix: rpb[64][64] bf16 -----------------------
// rows 0..26 = rph, rows 32..58 = rpw, rest zero
__global__ __launch_bounds__(256) void k_prep_rpb(const float* __restrict__ rph,
                                                  const float* __restrict__ rpw,
                                                  u16* __restrict__ rpb) {
  int idx = blockIdx.x * 256 + threadIdx.x;
  if (idx >= 4096) return;
  int p = idx >> 6, c = idx & 63;
  float v = 0.f;
  if (p < 27) v = rph[p * 64 + c];
  else if (p >= 32 && p < 59) v = rpw[(p - 32) * 64 + c];
  rpb[idx] = f2bf(v);
}

// --------------- bf16 gemm_bt: C[M][N] = A[M][K] * B[N][K]^T --------------
// MODE 0: qkv epilogue (q,k row-major; v transposed [bh][64][196]); MODE 1: proj
template <int MODE>
__global__ __launch_bounds__(256) void k_gemm(const u16* __restrict__ A,
                                              const u16* __restrict__ Bm,
                                              const float* __restrict__ bias,
                                              u16* __restrict__ o0,
                                              u16* __restrict__ o1,
                                              u16* __restrict__ o2,
                                              float* __restrict__ of,
                                              int ntn, int swq, int swr) {
  __shared__ u16 a_sm[128 * 32];
  __shared__ u16 b_sm[128 * 32];
  const int tid = threadIdx.x, lane = tid & 63, wid = tid >> 6;
  // bijective XCD swizzle (m204)
  int orig = blockIdx.x;
  int xcd = orig & 7, jj = orig >> 3;
  int wg = (xcd < swr ? xcd * (swq + 1) : swr * (swq + 1) + (xcd - swr) * swq) + jj;
  const int tn = wg % ntn, tm = wg / ntn;
  const int lr = lane & 15, lg = lane >> 4;
  const int wm = wid >> 1, wn = wid & 1;

  const int o0b = wid * 2048 + lane * 16;
  const int o1b = o0b + 1024;
  const char* gA0 = (const char*)A + (size_t)(tm * 128 + (o0b >> 6)) * (KDIM * 2) + (o0b & 63);
  const char* gA1 = (const char*)A + (size_t)(tm * 128 + (o1b >> 6)) * (KDIM * 2) + (o1b & 63);
  const char* gB0 = (const char*)Bm + (size_t)(tn * 128 + (o0b >> 6)) * (KDIM * 2) + (o0b & 63);
  const char* gB1 = (const char*)Bm + (size_t)(tn * 128 + (o1b >> 6)) * (KDIM * 2) + (o1b & 63);
  char* lA0 = (char*)a_sm + wid * 2048;
  char* lA1 = lA0 + 1024;
  char* lB0 = (char*)b_sm + wid * 2048;
  char* lB1 = lB0 + 1024;

  f32x4 acc[4][4];
#pragma unroll
  for (int m = 0; m < 4; m++)
#pragma unroll
    for (int n = 0; n < 4; n++) acc[m][n] = zero4();

  for (int kt = 0; kt < KDIM / 32; kt++) {
    if (kt) __syncthreads();
    glds16(gA0 + kt * 64, lA0);
    glds16(gA1 + kt * 64, lA1);
    glds16(gB0 + kt * 64, lB0);
    glds16(gB1 + kt * 64, lB1);
    __syncthreads();
    bf16x8 af[4], bfr[4];
#pragma unroll
    for (int m = 0; m < 4; m++)
      af[m] = *(const bf16x8*)((const char*)a_sm + (wm * 64 + m * 16 + lr) * 64 + lg * 16);
#pragma unroll
    for (int n = 0; n < 4; n++)
      bfr[n] = *(const bf16x8*)((const char*)b_sm + (wn * 64 + n * 16 + lr) * 64 + lg * 16);
#pragma unroll
    for (int m = 0; m < 4; m++)
#pragma unroll
      for (int n = 0; n < 4; n++)
        acc[m][n] = __builtin_amdgcn_mfma_f32_16x16x32_bf16(af[m], bfr[n], acc[m][n], 0, 0, 0);
  }

#pragma unroll
  for (int n = 0; n < 4; n++) {
    int ng = tn * 128 + wn * 64 + n * 16 + lr;
    float bv = bias[ng];
#pragma unroll
    for (int m = 0; m < 4; m++) {
#pragma unroll
      for (int r = 0; r < 4; r++) {
        int mg = tm * 128 + wm * 64 + m * 16 + lg * 4 + r;
        if (mg < MROWS) {
          float val = acc[m][n][r] + bv;
          if (MODE == 0) {
            int which = ng / 768;
            int rem = ng - which * 768;
            int head = rem >> 6, d = rem & 63;
            int bi = mg / 196, i = mg - bi * 196;
            int bh = bi * 12 + head;
            if (which == 0)
              o0[((size_t)bh * 196 + i) * 64 + d] = f2bf(val);
            else if (which == 1)
              o1[((size_t)bh * 196 + i) * 64 + d] = f2bf(val);
            else
              o2[((size_t)bh * 64 + d) * 196 + i] = f2bf(val);  // v transposed
          } else {
            of[(size_t)mg * 768 + ng] = val;
          }
        }
      }
    }
  }
}

// ---------------- fused attention v2 ---------------------------------------
// LDS: K [208][128B] swizzled, VT [64][448B] swizzled, T [208][112B]
#define AK 0
#define AV 26624
#define AT 55296
#define SMT 78592

__global__ __launch_bounds__(256, 2) void k_attn(const u16* __restrict__ qb,
                                                 const u16* __restrict__ kb,
                                                 const u16* __restrict__ vt,
                                                 const u16* __restrict__ rpb,
                                                 u16* __restrict__ ao) {
  extern __shared__ char sm[];
  const int tid = threadIdx.x;
  const int bh = blockIdx.x;
  const int lane = tid & 63, wv = tid >> 6;
  const int lr = lane & 15, lg = lane >> 4;
  const u16* qg = qb + (size_t)bh * 12544;
  const u16* kg = kb + (size_t)bh * 12544;
  const u16* vg = vt + (size_t)bh * 12544;

  // ---- stage K via global_load_lds, pre-swizzled source (T2/m173) ----
  for (int o = tid * 16; o < 25088; o += 4096) {
    int row = o >> 7, cb = o & 127;
    glds16((const char*)kg + row * 128 + (cb ^ ((row & 7) << 4)), sm + AK + o);
  }
  // ---- stage V^T (global [64][196] -> LDS [64][448B] swizzled) ----
  for (int ch = tid; ch < 1600; ch += 256) {
    int d = ch / 25, i = ch - d * 25;
    const char* src = (const char*)vg + d * 392 + i * 16;
    int dst = (d * 448 + i * 16) ^ ((d & 7) << 4);
    if (i < 24) {
      i32x2 va = *(const i32x2*)src;
      i32x2 vb = *(const i32x2*)(src + 8);
      *(i32x2*)(sm + AV + dst) = va;
      *(i32x2*)(sm + AV + dst + 8) = vb;
    } else {
      i32x2 va = *(const i32x2*)src;  // cols 192..195
      *(i32x2*)(sm + AV + dst) = va;
    }
  }
  {  // zero VT cols 196..223
    int d = tid >> 2, part = tid & 3;
    if (part == 0) {
      i32x2 z; z[0] = 0; z[1] = 0;
      *(i32x2*)(sm + AV + ((d * 448 + 392) ^ ((d & 7) << 4))) = z;
    } else {
      i32x4 z; z[0] = 0; z[1] = 0; z[2] = 0; z[3] = 0;
      *(i32x4*)(sm + AV + ((d * 448 + 384 + part * 16) ^ ((d & 7) << 4))) = z;
    }
  }
  __syncthreads();

  // rpb fragments (hoisted; shared across all q-tiles)
  bf16x8 rb0[4], rb1[4];
#pragma unroll
  for (int pt = 0; pt < 4; pt++) {
    rb0[pt] = *(const bf16x8*)((const char*)rpb + (pt * 16 + lr) * 128 + lg * 16);
    rb1[pt] = *(const bf16x8*)((const char*)rpb + (pt * 16 + lr) * 128 + 64 + lg * 16);
  }

  const int bi = bh / 12, head = bh - bi * 12;

  for (int qt = wv; qt < 13; qt += 4) {
    const int q = qt * 16 + lr;
    const int qc = q > 195 ? 195 : q;
    bf16x8 bq0 = *(const bf16x8*)((const char*)qg + qc * 128 + lg * 16);
    bf16x8 bq1 = *(const bf16x8*)((const char*)qg + qc * 128 + 64 + lg * 16);

    // ---- T-build via MFMA: T[qrow][col], own rows only (no barrier) ----
    {
      f32x4 td[4];
#pragma unroll
      for (int pt = 0; pt < 4; pt++) {
        td[pt] = zero4();
        td[pt] = __builtin_amdgcn_mfma_f32_16x16x32_bf16(bq0, rb0[pt], td[pt], 0, 0, 0);
        td[pt] = __builtin_amdgcn_mfma_f32_16x16x32_bf16(bq1, rb1[pt], td[pt], 0, 0, 0);
      }
#pragma unroll
      for (int pt = 0; pt < 4; pt++) {
        int p = pt * 16 + lr;
        int col = (p < 28) ? p : ((p >= 32 && p < 60) ? p - 4 : -1);
        if (col >= 0) {
#pragma unroll
          for (int r = 0; r < 4; r++) {
            int rowq = qt * 16 + lg * 4 + r;
            *(u16*)(sm + AT + rowq * 112 + col * 2) = f2bf(td[pt][r]);
          }
        }
      }
      asm volatile("s_waitcnt lgkmcnt(0)" ::: "memory");
    }

    // ---- swapped QK^T: s[j][r] = S[q = qt*16+lr][k = j*16+lg*4+r] ----
    f32x4 s[13];
#pragma unroll
    for (int j = 0; j < 13; j++) s[j] = zero4();
#pragma unroll
    for (int j = 0; j < 13; j++) {
      int kr = j * 16 + lr;
      bf16x8 ak0 = *(const bf16x8*)(sm + AK + ((kr * 128 + lg * 16) ^ ((kr & 7) << 4)));
      bf16x8 ak1 = *(const bf16x8*)(sm + AK + ((kr * 128 + 64 + lg * 16) ^ ((kr & 7) << 4)));
      s[j] = __builtin_amdgcn_mfma_f32_16x16x32_bf16(ak0, bq0, s[j], 0, 0, 0);
      s[j] = __builtin_amdgcn_mfma_f32_16x16x32_bf16(ak1, bq1, s[j], 0, 0, 0);
    }

    // ---- softmax (per-lane full row; reduce over lg via 2 shfl) ----
    const int hq = (q * 2341) >> 15;
    const int wq = q - hq * 14;
    const char* Trow = sm + AT + q * 112;
    float mx = -3.0e38f;
#pragma unroll
    for (int j = 0; j < 13; j++) {
#pragma unroll
      for (int r = 0; r < 4; r++) {
        int k = j * 16 + lg * 4 + r;
        float t = -3.0e38f;
        if (k < 196) {
          int kh = (k * 2341) >> 15;
          int kw = k - kh * 14;
          t = s[j][r] * 0.125f
            + bf2f(*(const u16*)(Trow + (hq - kh + 13) * 2))
            + bf2f(*(const u16*)(Trow + (wq - kw + 13 + 28) * 2));
        }
        s[j][r] = t;
        mx = fmaxf(mx, t);
      }
    }
    mx = fmaxf(mx, __shfl_xor(mx, 16));
    mx = fmaxf(mx, __shfl_xor(mx, 32));
    float sum = 0.f;
#pragma unroll
    for (int j = 0; j < 13; j++) {
#pragma unroll
      for (int r = 0; r < 4; r++) {
        int k = j * 16 + lg * 4 + r;
        float p = 0.f;
        if (k < 196) p = __expf(s[j][r] - mx);
        s[j][r] = p;
        sum += p;
      }
    }
    sum += __shfl_xor(sum, 16);
    sum += __shfl_xor(sum, 32);
    const float rs = 1.f / sum;

    // ---- pack normalized P into bf16-pair words ----
    u32 w[13][2];
#pragma unroll
    for (int j = 0; j < 13; j++) {
      w[j][0] = cvt_pk_bf16(s[j][0] * rs, s[j][1] * rs);
      w[j][1] = cvt_pk_bf16(s[j][2] * rs, s[j][3] * rs);
    }

    // ---- in-register repack to PV A-fragments + PV MFMA ----
    // target: pa[kk][e] = P[q=qt*16+lr][kk*32+lg*8+e]
    //   j = 2kk+(lg>>1); src lane lg_s = (lg&1)*2 + (e>>2); src r = e&3
    const int srcA = lr + ((lg & 1) * 2) * 16;
    const int srcB = srcA + 16;
    const bool hi = (lg >> 1) != 0;

    f32x4 ov[4];
#pragma unroll
    for (int d4 = 0; d4 < 4; d4++) ov[d4] = zero4();

#pragma unroll
    for (int kk = 0; kk < 7; kk++) {
      u32 W[4];
      if (kk < 6) {
#pragma unroll
        for (int m = 0; m < 4; m++) {
          int src = (m < 2) ? srcA : srcB;
          u32 ta = (u32)__shfl((int)w[2 * kk][m & 1], src);
          u32 tb = (u32)__shfl((int)w[2 * kk + 1][m & 1], src);
          W[m] = hi ? tb : ta;
        }
      } else {
#pragma unroll
        for (int m = 0; m < 4; m++) {
          int src = (m < 2) ? srcA : srcB;
          u32 ta = (u32)__shfl((int)w[12][m & 1], src);
          W[m] = hi ? 0u : ta;  // k>=208 is zero
        }
      }
      i32x4 wi; wi[0] = W[0]; wi[1] = W[1]; wi[2] = W[2]; wi[3] = W[3];
      bf16x8 pa = *(bf16x8*)&wi;
#pragma unroll
      for (int d4 = 0; d4 < 4; d4++) {
        int vr = d4 * 16 + lr;
        bf16x8 vf = *(const bf16x8*)(sm + AV + ((vr * 448 + kk * 64 + lg * 16) ^ ((vr & 7) << 4)));
        ov[d4] = __builtin_amdgcn_mfma_f32_16x16x32_bf16(pa, vf, ov[d4], 0, 0, 0);
      }
    }

    // ---- store (already normalized) ----
#pragma unroll
    for (int r = 0; r < 4; r++) {
      int i = qt * 16 + lg * 4 + r;
      if (i < 196) {
        size_t ro = ((size_t)(bi * 196 + i)) * 768 + head * 64 + lr;
#pragma unroll
        for (int d4 = 0; d4 < 4; d4++) {
          ao[ro + d4 * 16] = f2bf(ov[d4][r]);
        }
      }
    }
  }
}

// --------------------------------------------------------------------------
extern "C" void kernel_launch(void* const* d_in, const int* in_sizes, int n_in,
                              void* d_out, int out_size, void* d_ws, size_t ws_size,
                              hipStream_t stream) {
  const float* x = (const float*)d_in[0];
  const float* w_qkv = (const float*)d_in[1];
  const float* b_qkv = (const float*)d_in[2];
  const float* w_proj = (const float*)d_in[3];
  const float* b_proj = (const float*)d_in[4];
  const float* rph = (const float*)d_in[5];
  const float* rpw = (const float*)d_in[6];
  float* out = (float*)d_out;

  // workspace layout (aob aliases xb; rpb in xb's tail slack)
  char* ws = (char*)d_ws;
  u16* xb = (u16*)(ws + 0);                  // data 60,211,200 of 60,358,656
  u16* aob = (u16*)(ws + 0);                 // alias
  u16* rpb = (u16*)(ws + 60211200);          // 8,192 (inside xb pad slack)
  u16* wqkvT = (u16*)(ws + 60358656);        // 3,538,944
  u16* wprojT = (u16*)(ws + 63897600);       // 1,179,648
  u16* qbuf = (u16*)(ws + 65077248);         // 60,211,200
  u16* kbuf = (u16*)(ws + 125288448);        // 60,211,200
  u16* vtg = (u16*)(ws + 185499648);         // 60,211,200 ([bh][64][196])
  if (ws_size < 245710848ULL) return;        // fail cleanly, never OOB

  k_prep_rpb<<<16, 256, 0, stream>>>(rph, rpw, rpb);
  k_convert_x<<<14700, 256, 0, stream>>>(x, xb);
  k_transpose_w<<<6912, 256, 0, stream>>>(w_qkv, wqkvT, 768, 2304, 768 * 2304);
  k_transpose_w<<<2304, 256, 0, stream>>>(w_proj, wprojT, 768, 768, 768 * 768);

  // qkv: 18 n-tiles x 307 m-tiles = 5526 blocks; swq=690, swr=6
  k_gemm<0><<<5526, 256, 0, stream>>>(xb, wqkvT, b_qkv, qbuf, kbuf, vtg, nullptr,
                                      18, 690, 6);

  hipFuncSetAttribute((const void*)k_attn, hipFuncAttributeMaxDynamicSharedMemorySize, SMT);
  k_attn<<<2400, 256, SMT, stream>>>(qbuf, kbuf, vtg, rpb, aob);

  // proj: 6 x 307 = 1842 blocks; swq=230, swr=2
  k_gemm<1><<<1842, 256, 0, stream>>>(aob, wprojT, b_proj, nullptr, nullptr, nullptr, out,
                                      6, 230, 2);
}